// Round 1
// baseline (1499.967 us; speedup 1.0000x reference)
//
#include <hip/hip_runtime.h>

// Problem constants (fixed by reference)
#define B_TOTAL 8192
#define F_IN    1024
#define U_UNITS 256
#define NACT    16
#define HID     8

constexpr int BM = 128, BN = 128, BK = 16;

// Fused coagent layer: GEMM (h_pre = X @ W0^T) with epilogue running the
// per-unit tiny MLP (+bias, relu, 8x8, relu, 16x8, argmax) entirely on-chip.
// Output written TRANSPOSED: outT[u][b], so the next layer's A-staging and
// this layer's stores are coalesced.
//   X            : row-major [B, K_TOTAL]          (X_TRANSPOSED=false)
//                  or transposed [K_TOTAL, B]      (X_TRANSPOSED=true)
//   W0           : [U*HID, K_TOTAL] row-major (i.e. W0_x reshaped)
//   b0           : [U*HID]
//   W1,b1,W2,b2  : [U,8,8],[U,8],[U,16,8],[U,16]
template<int K_TOTAL, bool X_TRANSPOSED>
__global__ __launch_bounds__(256, 2)
void coagent_kernel(const float* __restrict__ X,
                    const float* __restrict__ W0,
                    const float* __restrict__ b0,
                    const float* __restrict__ W1,
                    const float* __restrict__ b1,
                    const float* __restrict__ W2,
                    const float* __restrict__ b2,
                    float* __restrict__ outT)
{
    struct SMemGemm { float As[BK][BM + 4]; float Bs[BK][BN + 4]; };
    union SMem { SMemGemm g; float Hs[BM][65]; };
    __shared__ SMem sm;

    const int tid = threadIdx.x;
    const int tx = tid & 15;        // 16 col-groups
    const int ty = tid >> 4;        // 16 row-groups
    const int m0 = blockIdx.y * BM; // batch-row tile
    const int n0 = blockIdx.x * BN; // (u,h) col tile -> 16 units

    float acc[8][8];
#pragma unroll
    for (int i = 0; i < 8; ++i)
#pragma unroll
        for (int j = 0; j < 8; ++j) acc[i][j] = 0.f;

    for (int k0 = 0; k0 < K_TOTAL; k0 += BK) {
        __syncthreads();
        // ---- stage A tile into As[k][m] (transposed in LDS) ----
        if (X_TRANSPOSED) {
#pragma unroll
            for (int l = tid; l < (BM * BK) / 4; l += 256) {
                const int k = l >> 5;       // 0..15
                const int q = l & 31;       // m-quad 0..31
                const float4 v = *reinterpret_cast<const float4*>(
                    &X[(size_t)(k0 + k) * B_TOTAL + m0 + 4 * q]);
                *reinterpret_cast<float4*>(&sm.g.As[k][4 * q]) = v;
            }
        } else {
#pragma unroll
            for (int l = tid; l < (BM * BK) / 4; l += 256) {
                const int row = l >> 2;     // m 0..127
                const int c   = l & 3;      // k-quad 0..3
                const float4 v = *reinterpret_cast<const float4*>(
                    &X[(size_t)(m0 + row) * K_TOTAL + k0 + 4 * c]);
                sm.g.As[4 * c + 0][row] = v.x;
                sm.g.As[4 * c + 1][row] = v.y;
                sm.g.As[4 * c + 2][row] = v.z;
                sm.g.As[4 * c + 3][row] = v.w;
            }
        }
        // ---- stage B tile (W0 rows) into Bs[k][n] ----
#pragma unroll
        for (int l = tid; l < (BN * BK) / 4; l += 256) {
            const int row = l >> 2;
            const int c   = l & 3;
            const float4 v = *reinterpret_cast<const float4*>(
                &W0[(size_t)(n0 + row) * K_TOTAL + k0 + 4 * c]);
            sm.g.Bs[4 * c + 0][row] = v.x;
            sm.g.Bs[4 * c + 1][row] = v.y;
            sm.g.Bs[4 * c + 2][row] = v.z;
            sm.g.Bs[4 * c + 3][row] = v.w;
        }
        __syncthreads();
        // ---- 8x8 register-tile FMA ----
#pragma unroll
        for (int k = 0; k < BK; ++k) {
            float a[8], bb[8];
            *reinterpret_cast<float4*>(&a[0])  = *reinterpret_cast<float4*>(&sm.g.As[k][4 * ty]);
            *reinterpret_cast<float4*>(&a[4])  = *reinterpret_cast<float4*>(&sm.g.As[k][64 + 4 * ty]);
            *reinterpret_cast<float4*>(&bb[0]) = *reinterpret_cast<float4*>(&sm.g.Bs[k][4 * tx]);
            *reinterpret_cast<float4*>(&bb[4]) = *reinterpret_cast<float4*>(&sm.g.Bs[k][64 + 4 * tx]);
#pragma unroll
            for (int i = 0; i < 8; ++i)
#pragma unroll
                for (int j = 0; j < 8; ++j)
                    acc[i][j] += a[i] * bb[j];
        }
    }

    // ---- epilogue: two halves of 64 cols (8 units each) ----
    const int ub_base = n0 >> 3; // first unit of this tile
    for (int half = 0; half < 2; ++half) {
        __syncthreads();
#pragma unroll
        for (int i = 0; i < 8; ++i) {
            const int row = (i < 4) ? (4 * ty + i) : (64 + 4 * ty + (i - 4));
#pragma unroll
            for (int j = 0; j < 4; ++j)
                sm.Hs[row][4 * tx + j] = acc[i][4 * half + j];
        }
        __syncthreads();
        // 128 b x 8 units = 1024 (b,u) pairs; 4 per thread, lane-consecutive b
#pragma unroll
        for (int p = 0; p < 4; ++p) {
            const int pair = (p << 8) + tid;
            const int ul = pair >> 7;       // unit-local 0..7 (wave-uniform)
            const int bl = pair & 127;      // batch-local, lane-consecutive
            const int u  = ub_base + half * 8 + ul;

            float h[HID];
#pragma unroll
            for (int j = 0; j < HID; ++j)
                h[j] = fmaxf(sm.Hs[bl][ul * 8 + j] + b0[u * 8 + j], 0.f);

            float h2[HID];
#pragma unroll
            for (int g = 0; g < HID; ++g) {
                float s = b1[u * 8 + g];
#pragma unroll
                for (int j = 0; j < HID; ++j)
                    s += h[j] * W1[u * 64 + g * 8 + j];
                h2[g] = fmaxf(s, 0.f);
            }

            // argmax over 16 actions, first-max-wins (matches np.argmax)
            float best = b2[u * 16];
            {
#pragma unroll
                for (int j = 0; j < HID; ++j)
                    best += h2[j] * W2[u * 128 + j];
            }
            int bi = 0;
#pragma unroll
            for (int a = 1; a < NACT; ++a) {
                float s = b2[u * 16 + a];
#pragma unroll
                for (int j = 0; j < HID; ++j)
                    s += h2[j] * W2[u * 128 + a * 8 + j];
                if (s > best) { best = s; bi = a; }
            }
            outT[(size_t)u * B_TOTAL + m0 + bl] = (float)bi;
        }
    }
}

// Policy head: out[b] = PW2 @ relu(PW1 @ relu(PW0 @ a1[b] + Pb0) + Pb1) + Pb2
// a1 is stored transposed [U][B] -> loads coalesced across lanes.
__global__ __launch_bounds__(256)
void policy_kernel(const float* __restrict__ A1T,
                   const float* __restrict__ PW0, const float* __restrict__ Pb0,
                   const float* __restrict__ PW1, const float* __restrict__ Pb1,
                   const float* __restrict__ PW2, const float* __restrict__ Pb2,
                   float* __restrict__ out)
{
    const int b = blockIdx.x * blockDim.x + threadIdx.x;
    if (b >= B_TOTAL) return;

    float hp[HID];
#pragma unroll
    for (int j = 0; j < HID; ++j) hp[j] = Pb0[j];

    for (int u = 0; u < U_UNITS; ++u) {
        const float v = A1T[(size_t)u * B_TOTAL + b];
#pragma unroll
        for (int j = 0; j < HID; ++j)
            hp[j] += v * PW0[j * U_UNITS + u];
    }

    float h[HID];
#pragma unroll
    for (int j = 0; j < HID; ++j) h[j] = fmaxf(hp[j], 0.f);

    float h2[HID];
#pragma unroll
    for (int g = 0; g < HID; ++g) {
        float s = Pb1[g];
#pragma unroll
        for (int j = 0; j < HID; ++j)
            s += h[j] * PW1[g * 8 + j];
        h2[g] = fmaxf(s, 0.f);
    }

    float o = Pb2[0];
#pragma unroll
    for (int j = 0; j < HID; ++j)
        o += h2[j] * PW2[j];
    out[b] = o;
}

extern "C" void kernel_launch(void* const* d_in, const int* in_sizes, int n_in,
                              void* d_out, int out_size, void* d_ws, size_t ws_size,
                              hipStream_t stream)
{
    const float* state = (const float*)d_in[0];
    const float* W0_0  = (const float*)d_in[1];   // [256,8,1024] -> [2048,1024]
    const float* b0_0  = (const float*)d_in[2];
    const float* W1_0  = (const float*)d_in[3];
    const float* b1_0  = (const float*)d_in[4];
    const float* W2_0  = (const float*)d_in[5];
    const float* b2_0  = (const float*)d_in[6];
    const float* W0_1  = (const float*)d_in[7];   // [256,8,256] -> [2048,256]
    const float* b0_1  = (const float*)d_in[8];
    const float* W1_1  = (const float*)d_in[9];
    const float* b1_1  = (const float*)d_in[10];
    const float* W2_1  = (const float*)d_in[11];
    const float* b2_1  = (const float*)d_in[12];
    const float* PW0   = (const float*)d_in[13];
    const float* Pb0   = (const float*)d_in[14];
    const float* PW1   = (const float*)d_in[15];
    const float* Pb1   = (const float*)d_in[16];
    const float* PW2   = (const float*)d_in[17];
    const float* Pb2   = (const float*)d_in[18];

    float* a0T = (float*)d_ws;                       // [256][8192]
    float* a1T = a0T + (size_t)U_UNITS * B_TOTAL;    // [256][8192]

    dim3 grid((U_UNITS * HID) / BN, B_TOTAL / BM);   // (16, 64)

    coagent_kernel<F_IN, false><<<grid, 256, 0, stream>>>(
        state, W0_0, b0_0, W1_0, b1_0, W2_0, b2_0, a0T);

    coagent_kernel<U_UNITS, true><<<grid, 256, 0, stream>>>(
        a0T, W0_1, b0_1, W1_1, b1_1, W2_1, b2_1, a1T);

    policy_kernel<<<B_TOTAL / 256, 256, 0, stream>>>(
        a1T, PW0, Pb0, PW1, Pb1, PW2, Pb2, (float*)d_out);
}

// Round 3
// 446.095 us; speedup vs baseline: 3.3624x; 3.3624x over previous
//
#include <hip/hip_runtime.h>
#include <cstring>

// Problem constants (fixed by reference)
#define B_TOTAL 8192
#define F_IN    1024
#define U_UNITS 256
#define NACT    16
#define HID     8

typedef float    f32x4  __attribute__((ext_vector_type(4)));
typedef _Float16 half8  __attribute__((ext_vector_type(8)));
typedef _Float16 half4  __attribute__((ext_vector_type(4)));

// ============================================================================
// MFMA path: fp16 split-2 emulation of fp32 GEMM.
// Low parts are pre-scaled by 2048 so they stay in fp16 NORMAL range
// (unscaled lows of N(0,1)/32 weights land in the subnormal band -> flushed/
// quantized by the matrix pipe -> argmax flips; this was R2's failure).
// Cross terms accumulate in a second accumulator at scale 2^-11.
// ============================================================================

// fp32 -> (high fp16, low fp16 * 2048), 4 elems/thread
__global__ __launch_bounds__(256)
void split2_kernel(const float* __restrict__ src,
                   _Float16* __restrict__ dh, _Float16* __restrict__ dl, int n4)
{
    int i = blockIdx.x * blockDim.x + threadIdx.x;
    if (i >= n4) return;
    f32x4 v = reinterpret_cast<const f32x4*>(src)[i];
    half4 h, l;
#pragma unroll
    for (int j = 0; j < 4; ++j) {
        h[j] = (_Float16)v[j];
        l[j] = (_Float16)((v[j] - (float)h[j]) * 2048.0f);
    }
    reinterpret_cast<half4*>(dh)[i] = h;
    reinterpret_cast<half4*>(dl)[i] = l;
}

constexpr int BM = 128, BN = 128, BK = 32;
constexpr int PADK = BK + 8;   // +8 halves: fragment reads land 2-way max on banks

// h_pre = X @ W^T via fp16-split MFMA, fused per-unit MLP (+b0,relu,8x8,relu,
// 16x8,argmax) epilogue.
//  A_SPLIT:   X has a (scaled) low part (layer 0). Else X is exact fp16 (layer 1).
//  OUT_TF32:  write fp32 transposed [U][B] (layer 1, feeds policy head);
//             else write fp16 row-major [B][U] (layer 0, feeds layer 1 A).
template<int K_TOTAL, bool A_SPLIT, bool OUT_TF32>
__global__ __launch_bounds__(256, 2)
void coagent_mfma(const _Float16* __restrict__ Ahg, const _Float16* __restrict__ Alg,
                  const _Float16* __restrict__ Bhg, const _Float16* __restrict__ Blg,
                  const float* __restrict__ b0, const float* __restrict__ W1,
                  const float* __restrict__ b1, const float* __restrict__ W2,
                  const float* __restrict__ b2, void* __restrict__ outp)
{
    struct GemmBufs { _Float16 Ah[BM*PADK], Al[BM*PADK], Bh[BN*PADK], Bl[BN*PADK]; };
    struct EpiBufs  { float Hs[BM][65]; _Float16 ab[BM*8]; };
    union SMem { GemmBufs g; EpiBufs e; };
    __shared__ SMem sm;

    const int tid  = threadIdx.x;
    const int wave = tid >> 6;
    const int lane = tid & 63;
    const int quad = lane >> 4;
    const int l15  = lane & 15;
    const int wm   = (wave >> 1) * 64;   // wave tile 64x64
    const int wn   = (wave & 1) * 64;
    const int m0   = blockIdx.y * BM;
    const int n0   = blockIdx.x * BN;

    f32x4 acc1[4][4];   // Ah*Bh            (scale 1)
    f32x4 acc2[4][4];   // Al'*Bh + Ah*Bl'  (scale 2^-11)
#pragma unroll
    for (int i = 0; i < 4; ++i)
#pragma unroll
        for (int j = 0; j < 4; ++j) { acc1[i][j] = {0.f,0.f,0.f,0.f}; acc2[i][j] = {0.f,0.f,0.f,0.f}; }

    for (int k0 = 0; k0 < K_TOTAL; k0 += BK) {
        __syncthreads();
        // ---- stage: 4 tiles of 128 rows x 32 halves (16B chunks, 2/thread) ----
#pragma unroll
        for (int i = 0; i < 2; ++i) {
            const int c   = tid + (i << 8);      // 0..511
            const int row = c >> 2;
            const int ko  = (c & 3) * 8;
            const int lo  = row * PADK + ko;
            const size_t ga = (size_t)(m0 + row) * K_TOTAL + k0 + ko;
            const size_t gb = (size_t)(n0 + row) * K_TOTAL + k0 + ko;
            *reinterpret_cast<half8*>(&sm.g.Ah[lo]) = *reinterpret_cast<const half8*>(&Ahg[ga]);
            if (A_SPLIT)
                *reinterpret_cast<half8*>(&sm.g.Al[lo]) = *reinterpret_cast<const half8*>(&Alg[ga]);
            *reinterpret_cast<half8*>(&sm.g.Bh[lo]) = *reinterpret_cast<const half8*>(&Bhg[gb]);
            *reinterpret_cast<half8*>(&sm.g.Bl[lo]) = *reinterpret_cast<const half8*>(&Blg[gb]);
        }
        __syncthreads();
        // ---- fragments + MFMA (one K=32 step, 2-3 passes) ----
        half8 af[4], bf[4], xf[4];
#pragma unroll
        for (int mt = 0; mt < 4; ++mt)
            af[mt] = *reinterpret_cast<const half8*>(
                &sm.g.Ah[(wm + mt * 16 + l15) * PADK + quad * 8]);
#pragma unroll
        for (int nt = 0; nt < 4; ++nt)
            bf[nt] = *reinterpret_cast<const half8*>(
                &sm.g.Bh[(wn + nt * 16 + l15) * PADK + quad * 8]);
#pragma unroll
        for (int mt = 0; mt < 4; ++mt)
#pragma unroll
            for (int nt = 0; nt < 4; ++nt)
                acc1[mt][nt] = __builtin_amdgcn_mfma_f32_16x16x32_f16(af[mt], bf[nt], acc1[mt][nt], 0, 0, 0);
        if (A_SPLIT) {
#pragma unroll
            for (int mt = 0; mt < 4; ++mt)
                xf[mt] = *reinterpret_cast<const half8*>(
                    &sm.g.Al[(wm + mt * 16 + l15) * PADK + quad * 8]);
#pragma unroll
            for (int mt = 0; mt < 4; ++mt)
#pragma unroll
                for (int nt = 0; nt < 4; ++nt)
                    acc2[mt][nt] = __builtin_amdgcn_mfma_f32_16x16x32_f16(xf[mt], bf[nt], acc2[mt][nt], 0, 0, 0);
        }
#pragma unroll
        for (int nt = 0; nt < 4; ++nt)
            xf[nt] = *reinterpret_cast<const half8*>(
                &sm.g.Bl[(wn + nt * 16 + l15) * PADK + quad * 8]);
#pragma unroll
        for (int mt = 0; mt < 4; ++mt)
#pragma unroll
            for (int nt = 0; nt < 4; ++nt)
                acc2[mt][nt] = __builtin_amdgcn_mfma_f32_16x16x32_f16(af[mt], xf[nt], acc2[mt][nt], 0, 0, 0);
    }

    // ---- epilogue: two 64-col halves (8 units each) ----
    const int ubase = n0 >> 3;
    for (int half = 0; half < 2; ++half) {
        __syncthreads();
        if ((wave & 1) == half) {        // 2 waves own these 64 cols
#pragma unroll
            for (int mt = 0; mt < 4; ++mt)
#pragma unroll
                for (int nt = 0; nt < 4; ++nt)
#pragma unroll
                    for (int r = 0; r < 4; ++r)
                        sm.e.Hs[wm + mt * 16 + quad * 4 + r][nt * 16 + l15] =
                            acc1[mt][nt][r] + acc2[mt][nt][r] * (1.0f / 2048.0f);
        }
        __syncthreads();
#pragma unroll
        for (int p = 0; p < 4; ++p) {
            const int pair = (p << 8) + tid;
            const int ul = pair >> 7;           // wave-uniform
            const int bl = pair & 127;          // lane-consecutive
            const int u  = ubase + half * 8 + ul;

            float h[HID];
#pragma unroll
            for (int j = 0; j < HID; ++j)
                h[j] = fmaxf(sm.e.Hs[bl][ul * 8 + j] + b0[u * 8 + j], 0.f);

            float h2[HID];
#pragma unroll
            for (int g = 0; g < HID; ++g) {
                float s = b1[u * 8 + g];
#pragma unroll
                for (int j = 0; j < HID; ++j)
                    s += h[j] * W1[u * 64 + g * 8 + j];
                h2[g] = fmaxf(s, 0.f);
            }

            float best = b2[u * 16];
#pragma unroll
            for (int j = 0; j < HID; ++j) best += h2[j] * W2[u * 128 + j];
            int bi = 0;
#pragma unroll
            for (int a = 1; a < NACT; ++a) {
                float s = b2[u * 16 + a];
#pragma unroll
                for (int j = 0; j < HID; ++j)
                    s += h2[j] * W2[u * 128 + a * 8 + j];
                if (s > best) { best = s; bi = a; }   // first-max-wins = np.argmax
            }

            if (OUT_TF32) {
                ((float*)outp)[(size_t)u * B_TOTAL + m0 + bl] = (float)bi;
            } else {
                sm.e.ab[bl * 8 + ul] = (_Float16)bi;
            }
        }
        if (!OUT_TF32) {
            __syncthreads();
            if (tid < 128) {   // coalesced 16B row-chunk writes of a0[b][u0..u0+8]
                float4 v = *reinterpret_cast<float4*>(&sm.e.ab[tid * 8]);
                *reinterpret_cast<float4*>(
                    &((_Float16*)outp)[(size_t)(m0 + tid) * U_UNITS + ubase + half * 8]) = v;
            }
        }
    }
}

// ============================================================================
// fp32 fallback path (round-1 kernels) — used only if ws_size is too small
// ============================================================================

constexpr int FBM = 128, FBN = 128, FBK = 16;

template<int K_TOTAL, bool X_TRANSPOSED>
__global__ __launch_bounds__(256, 2)
void coagent_kernel(const float* __restrict__ X, const float* __restrict__ W0,
                    const float* __restrict__ b0, const float* __restrict__ W1,
                    const float* __restrict__ b1, const float* __restrict__ W2,
                    const float* __restrict__ b2, float* __restrict__ outT)
{
    struct SMemGemm { float As[FBK][FBM + 4]; float Bs[FBK][FBN + 4]; };
    union SMem { SMemGemm g; float Hs[FBM][65]; };
    __shared__ SMem sm;

    const int tid = threadIdx.x;
    const int tx = tid & 15, ty = tid >> 4;
    const int m0 = blockIdx.y * FBM, n0 = blockIdx.x * FBN;

    float acc[8][8];
#pragma unroll
    for (int i = 0; i < 8; ++i)
#pragma unroll
        for (int j = 0; j < 8; ++j) acc[i][j] = 0.f;

    for (int k0 = 0; k0 < K_TOTAL; k0 += FBK) {
        __syncthreads();
        if (X_TRANSPOSED) {
#pragma unroll
            for (int l = tid; l < (FBM * FBK) / 4; l += 256) {
                const int k = l >> 5, q = l & 31;
                const float4 v = *reinterpret_cast<const float4*>(
                    &X[(size_t)(k0 + k) * B_TOTAL + m0 + 4 * q]);
                *reinterpret_cast<float4*>(&sm.g.As[k][4 * q]) = v;
            }
        } else {
#pragma unroll
            for (int l = tid; l < (FBM * FBK) / 4; l += 256) {
                const int row = l >> 2, c = l & 3;
                const float4 v = *reinterpret_cast<const float4*>(
                    &X[(size_t)(m0 + row) * K_TOTAL + k0 + 4 * c]);
                sm.g.As[4 * c + 0][row] = v.x; sm.g.As[4 * c + 1][row] = v.y;
                sm.g.As[4 * c + 2][row] = v.z; sm.g.As[4 * c + 3][row] = v.w;
            }
        }
#pragma unroll
        for (int l = tid; l < (FBN * FBK) / 4; l += 256) {
            const int row = l >> 2, c = l & 3;
            const float4 v = *reinterpret_cast<const float4*>(
                &W0[(size_t)(n0 + row) * K_TOTAL + k0 + 4 * c]);
            sm.g.Bs[4 * c + 0][row] = v.x; sm.g.Bs[4 * c + 1][row] = v.y;
            sm.g.Bs[4 * c + 2][row] = v.z; sm.g.Bs[4 * c + 3][row] = v.w;
        }
        __syncthreads();
#pragma unroll
        for (int k = 0; k < FBK; ++k) {
            float a[8], bb[8];
            *reinterpret_cast<float4*>(&a[0])  = *reinterpret_cast<float4*>(&sm.g.As[k][4 * ty]);
            *reinterpret_cast<float4*>(&a[4])  = *reinterpret_cast<float4*>(&sm.g.As[k][64 + 4 * ty]);
            *reinterpret_cast<float4*>(&bb[0]) = *reinterpret_cast<float4*>(&sm.g.Bs[k][4 * tx]);
            *reinterpret_cast<float4*>(&bb[4]) = *reinterpret_cast<float4*>(&sm.g.Bs[k][64 + 4 * tx]);
#pragma unroll
            for (int i = 0; i < 8; ++i)
#pragma unroll
                for (int j = 0; j < 8; ++j) acc[i][j] += a[i] * bb[j];
        }
    }

    const int ub_base = n0 >> 3;
    for (int half = 0; half < 2; ++half) {
        __syncthreads();
#pragma unroll
        for (int i = 0; i < 8; ++i) {
            const int row = (i < 4) ? (4 * ty + i) : (64 + 4 * ty + (i - 4));
#pragma unroll
            for (int j = 0; j < 4; ++j)
                sm.Hs[row][4 * tx + j] = acc[i][4 * half + j];
        }
        __syncthreads();
#pragma unroll
        for (int p = 0; p < 4; ++p) {
            const int pair = (p << 8) + tid;
            const int ul = pair >> 7, bl = pair & 127;
            const int u = ub_base + half * 8 + ul;
            float h[HID];
#pragma unroll
            for (int j = 0; j < HID; ++j)
                h[j] = fmaxf(sm.Hs[bl][ul * 8 + j] + b0[u * 8 + j], 0.f);
            float h2[HID];
#pragma unroll
            for (int g = 0; g < HID; ++g) {
                float s = b1[u * 8 + g];
#pragma unroll
                for (int j = 0; j < HID; ++j) s += h[j] * W1[u * 64 + g * 8 + j];
                h2[g] = fmaxf(s, 0.f);
            }
            float best = b2[u * 16];
#pragma unroll
            for (int j = 0; j < HID; ++j) best += h2[j] * W2[u * 128 + j];
            int bi = 0;
#pragma unroll
            for (int a = 1; a < NACT; ++a) {
                float s = b2[u * 16 + a];
#pragma unroll
                for (int j = 0; j < HID; ++j) s += h2[j] * W2[u * 128 + a * 8 + j];
                if (s > best) { best = s; bi = a; }
            }
            outT[(size_t)u * B_TOTAL + m0 + bl] = (float)bi;
        }
    }
}

// Policy head (reads a1T fp32 [U][B], coalesced across lanes)
__global__ __launch_bounds__(256)
void policy_kernel(const float* __restrict__ A1T,
                   const float* __restrict__ PW0, const float* __restrict__ Pb0,
                   const float* __restrict__ PW1, const float* __restrict__ Pb1,
                   const float* __restrict__ PW2, const float* __restrict__ Pb2,
                   float* __restrict__ out)
{
    const int b = blockIdx.x * blockDim.x + threadIdx.x;
    if (b >= B_TOTAL) return;
    float hp[HID];
#pragma unroll
    for (int j = 0; j < HID; ++j) hp[j] = Pb0[j];
    for (int u = 0; u < U_UNITS; ++u) {
        const float v = A1T[(size_t)u * B_TOTAL + b];
#pragma unroll
        for (int j = 0; j < HID; ++j) hp[j] += v * PW0[j * U_UNITS + u];
    }
    float h[HID];
#pragma unroll
    for (int j = 0; j < HID; ++j) h[j] = fmaxf(hp[j], 0.f);
    float h2[HID];
#pragma unroll
    for (int g = 0; g < HID; ++g) {
        float s = Pb1[g];
#pragma unroll
        for (int j = 0; j < HID; ++j) s += h[j] * PW1[g * 8 + j];
        h2[g] = fmaxf(s, 0.f);
    }
    float o = Pb2[0];
#pragma unroll
    for (int j = 0; j < HID; ++j) o += h2[j] * PW2[j];
    out[b] = o;
}

// ============================================================================

extern "C" void kernel_launch(void* const* d_in, const int* in_sizes, int n_in,
                              void* d_out, int out_size, void* d_ws, size_t ws_size,
                              hipStream_t stream)
{
    const float* state = (const float*)d_in[0];
    const float* W0_0  = (const float*)d_in[1];
    const float* b0_0  = (const float*)d_in[2];
    const float* W1_0  = (const float*)d_in[3];
    const float* b1_0  = (const float*)d_in[4];
    const float* W2_0  = (const float*)d_in[5];
    const float* b2_0  = (const float*)d_in[6];
    const float* W0_1  = (const float*)d_in[7];
    const float* b0_1  = (const float*)d_in[8];
    const float* W1_1  = (const float*)d_in[9];
    const float* b1_1  = (const float*)d_in[10];
    const float* W2_1  = (const float*)d_in[11];
    const float* b2_1  = (const float*)d_in[12];
    const float* PW0   = (const float*)d_in[13];
    const float* Pb0   = (const float*)d_in[14];
    const float* PW1   = (const float*)d_in[15];
    const float* Pb1   = (const float*)d_in[16];
    const float* PW2   = (const float*)d_in[17];
    const float* Pb2   = (const float*)d_in[18];

    // ws layout (bytes)
    const size_t SZ_STATE = (size_t)B_TOTAL * F_IN;        // elems
    const size_t SZ_W00   = (size_t)U_UNITS * HID * F_IN;
    const size_t SZ_W01   = (size_t)U_UNITS * HID * U_UNITS;
    const size_t NEED = (2 * SZ_STATE + 2 * SZ_W00 + 2 * SZ_W01
                         + (size_t)B_TOTAL * U_UNITS) * 2            // fp16 parts + a0
                        + (size_t)U_UNITS * B_TOTAL * 4;             // a1T fp32

    if (ws_size >= NEED) {
        char* p = (char*)d_ws;
        _Float16* state_h = (_Float16*)p;                p += SZ_STATE * 2;
        _Float16* state_l = (_Float16*)p;                p += SZ_STATE * 2;
        _Float16* w00_h   = (_Float16*)p;                p += SZ_W00 * 2;
        _Float16* w00_l   = (_Float16*)p;                p += SZ_W00 * 2;
        _Float16* w01_h   = (_Float16*)p;                p += SZ_W01 * 2;
        _Float16* w01_l   = (_Float16*)p;                p += SZ_W01 * 2;
        _Float16* a0      = (_Float16*)p;                p += (size_t)B_TOTAL * U_UNITS * 2;
        float*    a1T     = (float*)p;

        split2_kernel<<<(int)(SZ_STATE / 4 + 255) / 256, 256, 0, stream>>>(state, state_h, state_l, (int)(SZ_STATE / 4));
        split2_kernel<<<(int)(SZ_W00 / 4 + 255) / 256, 256, 0, stream>>>(W0_0, w00_h, w00_l, (int)(SZ_W00 / 4));
        split2_kernel<<<(int)(SZ_W01 / 4 + 255) / 256, 256, 0, stream>>>(W0_1, w01_h, w01_l, (int)(SZ_W01 / 4));

        dim3 grid((U_UNITS * HID) / BN, B_TOTAL / BM);   // (16, 64)

        coagent_mfma<F_IN, true, false><<<grid, 256, 0, stream>>>(
            state_h, state_l, w00_h, w00_l, b0_0, W1_0, b1_0, W2_0, b2_0, (void*)a0);

        coagent_mfma<U_UNITS, false, true><<<grid, 256, 0, stream>>>(
            a0, nullptr, w01_h, w01_l, b0_1, W1_1, b1_1, W2_1, b2_1, (void*)a1T);

        policy_kernel<<<B_TOTAL / 256, 256, 0, stream>>>(
            a1T, PW0, Pb0, PW1, Pb1, PW2, Pb2, (float*)d_out);
    } else {
        // fp32 fallback (round-1 path, needs 16 MB ws)
        float* a0T = (float*)d_ws;
        float* a1T = a0T + (size_t)U_UNITS * B_TOTAL;
        dim3 grid((U_UNITS * HID) / FBN, B_TOTAL / FBM);
        coagent_kernel<F_IN, false><<<grid, 256, 0, stream>>>(
            state, W0_0, b0_0, W1_0, b1_0, W2_0, b2_0, a0T);
        coagent_kernel<U_UNITS, true><<<grid, 256, 0, stream>>>(
            a0T, W0_1, b0_1, W1_1, b1_1, W2_1, b2_1, a1T);
        policy_kernel<<<B_TOTAL / 256, 256, 0, stream>>>(
            a1T, PW0, Pb0, PW1, Pb1, PW2, Pb2, (float*)d_out);
    }
}

// Round 4
// 440.533 us; speedup vs baseline: 3.4049x; 1.0126x over previous
//
#include <hip/hip_runtime.h>
#include <cstring>
#include <cstdint>

// Problem constants (fixed by reference)
#define B_TOTAL 8192
#define F_IN    1024
#define U_UNITS 256
#define NACT    16
#define HID     8

typedef float    f32x4  __attribute__((ext_vector_type(4)));
typedef _Float16 half8  __attribute__((ext_vector_type(8)));
typedef _Float16 half4  __attribute__((ext_vector_type(4)));

// ============================================================================
// MFMA path: fp16 split-2 emulation of fp32 GEMM.
// Low parts are pre-scaled by 2048 so they stay in fp16 NORMAL range
// (unscaled lows of N(0,1)/32 weights land in the subnormal band -> flushed ->
// argmax flips; R2's failure). Cross terms accumulate at scale 2^-11 in acc2.
//
// R4: fragment-ordered LDS ([part][tile][lane*16B]) staged via
// __builtin_amdgcn_global_load_lds (per-lane global gather -> lane-contiguous
// LDS). Fragment ds_read_b128 at lane*16 is perfectly sequential: zero bank
// conflicts, no staging VALU, no VGPR round-trip. MFMA math identical to R3.
// ============================================================================

// fp32 -> (high fp16, low fp16 * 2048), 4 elems/thread
__global__ __launch_bounds__(256)
void split2_kernel(const float* __restrict__ src,
                   _Float16* __restrict__ dh, _Float16* __restrict__ dl, int n4)
{
    int i = blockIdx.x * blockDim.x + threadIdx.x;
    if (i >= n4) return;
    f32x4 v = reinterpret_cast<const f32x4*>(src)[i];
    half4 h, l;
#pragma unroll
    for (int j = 0; j < 4; ++j) {
        h[j] = (_Float16)v[j];
        l[j] = (_Float16)((v[j] - (float)h[j]) * 2048.0f);
    }
    reinterpret_cast<half4*>(dh)[i] = h;
    reinterpret_cast<half4*>(dl)[i] = l;
}

constexpr int BM = 128, BN = 128, BK = 32;

#define GLOBAL_AS __attribute__((address_space(1)))
#define LDS_AS    __attribute__((address_space(3)))

// h_pre = X @ W^T via fp16-split MFMA, fused per-unit MLP (+b0,relu,8x8,relu,
// 16x8,argmax) epilogue.
//  A_SPLIT:   X has a (scaled) low part (layer 0). Else X is exact fp16 (layer 1).
//  OUT_TF32:  write fp32 transposed [U][B] (layer 1, feeds policy head);
//             else write fp16 row-major [B][U] (layer 0, feeds layer 1 A).
template<int K_TOTAL, bool A_SPLIT, bool OUT_TF32>
__global__ __launch_bounds__(256, 2)
void coagent_mfma(const _Float16* __restrict__ Ahg, const _Float16* __restrict__ Alg,
                  const _Float16* __restrict__ Bhg, const _Float16* __restrict__ Blg,
                  const float* __restrict__ b0, const float* __restrict__ W1,
                  const float* __restrict__ b1, const float* __restrict__ W2,
                  const float* __restrict__ b2, void* __restrict__ outp)
{
    // parts: 0=Ah 1=Al 2=Bh 3=Bl ; tile t = 16 rows ; 64 lanes x 8 halves
    struct GemmBufs { _Float16 t[4][8][512]; };
    struct EpiBufs  { float Hs[BM][65]; _Float16 ab[BM * 8]; };
    union SMem { GemmBufs g; EpiBufs e; };
    __shared__ SMem sm;

    const int tid  = threadIdx.x;
    const int wave = tid >> 6;
    const int lane = tid & 63;
    const int quad = lane >> 4;
    const int l15  = lane & 15;
    const int wm   = (wave >> 1) * 64;   // wave tile 64x64
    const int wn   = (wave & 1) * 64;
    const int m0   = blockIdx.y * BM;
    const int n0   = blockIdx.x * BN;

    // ---- per-wave staging descriptors (wave-uniform part/tile) ----
    constexpr int NL = A_SPLIT ? 8 : 6;
    const _Float16* gsrc[NL];
    _Float16*       ldst[NL];
#pragma unroll
    for (int j = 0; j < NL; ++j) {
        int part, tile;
        if (A_SPLIT) { part = wave; tile = j; }          // 4 parts x 8 tiles
        else { const int q = j * 4 + wave; part = q >> 3; tile = q & 7; } // 3 parts
        // physical buffer index: A_SPLIT: part as-is; else {Ah,Bh,Bl}={0,2,3}
        const int phys = A_SPLIT ? part : (part == 0 ? 0 : part + 1);
        const bool isA = (phys <= 1);
        const _Float16* src = (phys == 0) ? Ahg : (phys == 1) ? Alg
                            : (phys == 2) ? Bhg : Blg;
        const int row = (isA ? m0 : n0) + tile * 16 + l15;
        gsrc[j] = src + (size_t)row * K_TOTAL + quad * 8;   // per-lane gather addr
        ldst[j] = &sm.g.t[phys][tile][0];                   // wave-uniform LDS base
    }

    f32x4 acc1[4][4];   // Ah*Bh            (scale 1)
    f32x4 acc2[4][4];   // Al'*Bh + Ah*Bl'  (scale 2^-11)
#pragma unroll
    for (int i = 0; i < 4; ++i)
#pragma unroll
        for (int j = 0; j < 4; ++j) { acc1[i][j] = {0.f,0.f,0.f,0.f}; acc2[i][j] = {0.f,0.f,0.f,0.f}; }

    const int at = (wave >> 1) * 4;   // this wave's A tiles
    const int bt = (wave & 1) * 4;    // this wave's B tiles

    for (int k0 = 0; k0 < K_TOTAL; k0 += BK) {
        __syncthreads();   // previous iter's fragments consumed
#pragma unroll
        for (int j = 0; j < NL; ++j) {
            __builtin_amdgcn_global_load_lds(
                (const GLOBAL_AS void*)(gsrc[j] + k0),
                (LDS_AS void*)ldst[j], 16, 0, 0);
        }
        __syncthreads();   // compiler drains vmcnt before s_barrier

        half8 af[4], bf[4], xf[4];
#pragma unroll
        for (int mt = 0; mt < 4; ++mt)
            af[mt] = *reinterpret_cast<const half8*>(&sm.g.t[0][at + mt][lane * 8]);
#pragma unroll
        for (int nt = 0; nt < 4; ++nt)
            bf[nt] = *reinterpret_cast<const half8*>(&sm.g.t[2][bt + nt][lane * 8]);
#pragma unroll
        for (int mt = 0; mt < 4; ++mt)
#pragma unroll
            for (int nt = 0; nt < 4; ++nt)
                acc1[mt][nt] = __builtin_amdgcn_mfma_f32_16x16x32_f16(af[mt], bf[nt], acc1[mt][nt], 0, 0, 0);
        if (A_SPLIT) {
#pragma unroll
            for (int mt = 0; mt < 4; ++mt)
                xf[mt] = *reinterpret_cast<const half8*>(&sm.g.t[1][at + mt][lane * 8]);
#pragma unroll
            for (int mt = 0; mt < 4; ++mt)
#pragma unroll
                for (int nt = 0; nt < 4; ++nt)
                    acc2[mt][nt] = __builtin_amdgcn_mfma_f32_16x16x32_f16(xf[mt], bf[nt], acc2[mt][nt], 0, 0, 0);
        }
#pragma unroll
        for (int nt = 0; nt < 4; ++nt)
            xf[nt] = *reinterpret_cast<const half8*>(&sm.g.t[3][bt + nt][lane * 8]);
#pragma unroll
        for (int mt = 0; mt < 4; ++mt)
#pragma unroll
            for (int nt = 0; nt < 4; ++nt)
                acc2[mt][nt] = __builtin_amdgcn_mfma_f32_16x16x32_f16(af[mt], xf[nt], acc2[mt][nt], 0, 0, 0);
    }

    // ---- epilogue: two 64-col halves (8 units each) ----
    const int ubase = n0 >> 3;
    for (int half = 0; half < 2; ++half) {
        __syncthreads();
        if ((wave & 1) == half) {        // 2 waves own these 64 cols
#pragma unroll
            for (int mt = 0; mt < 4; ++mt)
#pragma unroll
                for (int nt = 0; nt < 4; ++nt)
#pragma unroll
                    for (int r = 0; r < 4; ++r)
                        sm.e.Hs[wm + mt * 16 + quad * 4 + r][nt * 16 + l15] =
                            acc1[mt][nt][r] + acc2[mt][nt][r] * (1.0f / 2048.0f);
        }
        __syncthreads();
#pragma unroll
        for (int p = 0; p < 4; ++p) {
            const int pair = (p << 8) + tid;
            const int ul = pair >> 7;           // wave-uniform
            const int bl = pair & 127;          // lane-consecutive
            const int u  = ubase + half * 8 + ul;

            float h[HID];
#pragma unroll
            for (int j = 0; j < HID; ++j)
                h[j] = fmaxf(sm.e.Hs[bl][ul * 8 + j] + b0[u * 8 + j], 0.f);

            float h2[HID];
#pragma unroll
            for (int g = 0; g < HID; ++g) {
                float s = b1[u * 8 + g];
#pragma unroll
                for (int j = 0; j < HID; ++j)
                    s += h[j] * W1[u * 64 + g * 8 + j];
                h2[g] = fmaxf(s, 0.f);
            }

            float best = b2[u * 16];
#pragma unroll
            for (int j = 0; j < HID; ++j) best += h2[j] * W2[u * 128 + j];
            int bi = 0;
#pragma unroll
            for (int a = 1; a < NACT; ++a) {
                float s = b2[u * 16 + a];
#pragma unroll
                for (int j = 0; j < HID; ++j)
                    s += h2[j] * W2[u * 128 + a * 8 + j];
                if (s > best) { best = s; bi = a; }   // first-max-wins = np.argmax
            }

            if (OUT_TF32) {
                ((float*)outp)[(size_t)u * B_TOTAL + m0 + bl] = (float)bi;
            } else {
                sm.e.ab[bl * 8 + ul] = (_Float16)bi;
            }
        }
        if (!OUT_TF32) {
            __syncthreads();
            if (tid < 128) {   // coalesced 16B row-chunk writes of a0[b][u0..u0+8]
                float4 v = *reinterpret_cast<float4*>(&sm.e.ab[tid * 8]);
                *reinterpret_cast<float4*>(
                    &((_Float16*)outp)[(size_t)(m0 + tid) * U_UNITS + ubase + half * 8]) = v;
            }
        }
    }
}

// ============================================================================
// fp32 fallback path (round-1 kernels) — used only if ws_size is too small
// ============================================================================

constexpr int FBM = 128, FBN = 128, FBK = 16;

template<int K_TOTAL, bool X_TRANSPOSED>
__global__ __launch_bounds__(256, 2)
void coagent_kernel(const float* __restrict__ X, const float* __restrict__ W0,
                    const float* __restrict__ b0, const float* __restrict__ W1,
                    const float* __restrict__ b1, const float* __restrict__ W2,
                    const float* __restrict__ b2, float* __restrict__ outT)
{
    struct SMemGemm { float As[FBK][FBM + 4]; float Bs[FBK][FBN + 4]; };
    union SMem { SMemGemm g; float Hs[FBM][65]; };
    __shared__ SMem sm;

    const int tid = threadIdx.x;
    const int tx = tid & 15, ty = tid >> 4;
    const int m0 = blockIdx.y * FBM, n0 = blockIdx.x * FBN;

    float acc[8][8];
#pragma unroll
    for (int i = 0; i < 8; ++i)
#pragma unroll
        for (int j = 0; j < 8; ++j) acc[i][j] = 0.f;

    for (int k0 = 0; k0 < K_TOTAL; k0 += FBK) {
        __syncthreads();
        if (X_TRANSPOSED) {
#pragma unroll
            for (int l = tid; l < (FBM * FBK) / 4; l += 256) {
                const int k = l >> 5, q = l & 31;
                const float4 v = *reinterpret_cast<const float4*>(
                    &X[(size_t)(k0 + k) * B_TOTAL + m0 + 4 * q]);
                *reinterpret_cast<float4*>(&sm.g.As[k][4 * q]) = v;
            }
        } else {
#pragma unroll
            for (int l = tid; l < (FBM * FBK) / 4; l += 256) {
                const int row = l >> 2, c = l & 3;
                const float4 v = *reinterpret_cast<const float4*>(
                    &X[(size_t)(m0 + row) * K_TOTAL + k0 + 4 * c]);
                sm.g.As[4 * c + 0][row] = v.x; sm.g.As[4 * c + 1][row] = v.y;
                sm.g.As[4 * c + 2][row] = v.z; sm.g.As[4 * c + 3][row] = v.w;
            }
        }
#pragma unroll
        for (int l = tid; l < (FBN * FBK) / 4; l += 256) {
            const int row = l >> 2, c = l & 3;
            const float4 v = *reinterpret_cast<const float4*>(
                &W0[(size_t)(n0 + row) * K_TOTAL + k0 + 4 * c]);
            sm.g.Bs[4 * c + 0][row] = v.x; sm.g.Bs[4 * c + 1][row] = v.y;
            sm.g.Bs[4 * c + 2][row] = v.z; sm.g.Bs[4 * c + 3][row] = v.w;
        }
        __syncthreads();
#pragma unroll
        for (int k = 0; k < FBK; ++k) {
            float a[8], bb[8];
            *reinterpret_cast<float4*>(&a[0])  = *reinterpret_cast<float4*>(&sm.g.As[k][4 * ty]);
            *reinterpret_cast<float4*>(&a[4])  = *reinterpret_cast<float4*>(&sm.g.As[k][64 + 4 * ty]);
            *reinterpret_cast<float4*>(&bb[0]) = *reinterpret_cast<float4*>(&sm.g.Bs[k][4 * tx]);
            *reinterpret_cast<float4*>(&bb[4]) = *reinterpret_cast<float4*>(&sm.g.Bs[k][64 + 4 * tx]);
#pragma unroll
            for (int i = 0; i < 8; ++i)
#pragma unroll
                for (int j = 0; j < 8; ++j) acc[i][j] += a[i] * bb[j];
        }
    }

    const int ub_base = n0 >> 3;
    for (int half = 0; half < 2; ++half) {
        __syncthreads();
#pragma unroll
        for (int i = 0; i < 8; ++i) {
            const int row = (i < 4) ? (4 * ty + i) : (64 + 4 * ty + (i - 4));
#pragma unroll
            for (int j = 0; j < 4; ++j)
                sm.Hs[row][4 * tx + j] = acc[i][4 * half + j];
        }
        __syncthreads();
#pragma unroll
        for (int p = 0; p < 4; ++p) {
            const int pair = (p << 8) + tid;
            const int ul = pair >> 7, bl = pair & 127;
            const int u = ub_base + half * 8 + ul;
            float h[HID];
#pragma unroll
            for (int j = 0; j < HID; ++j)
                h[j] = fmaxf(sm.Hs[bl][ul * 8 + j] + b0[u * 8 + j], 0.f);
            float h2[HID];
#pragma unroll
            for (int g = 0; g < HID; ++g) {
                float s = b1[u * 8 + g];
#pragma unroll
                for (int j = 0; j < HID; ++j) s += h[j] * W1[u * 64 + g * 8 + j];
                h2[g] = fmaxf(s, 0.f);
            }
            float best = b2[u * 16];
#pragma unroll
            for (int j = 0; j < HID; ++j) best += h2[j] * W2[u * 128 + j];
            int bi = 0;
#pragma unroll
            for (int a = 1; a < NACT; ++a) {
                float s = b2[u * 16 + a];
#pragma unroll
                for (int j = 0; j < HID; ++j) s += h2[j] * W2[u * 128 + a * 8 + j];
                if (s > best) { best = s; bi = a; }
            }
            outT[(size_t)u * B_TOTAL + m0 + bl] = (float)bi;
        }
    }
}

// Policy head (reads a1T fp32 [U][B], coalesced across lanes)
__global__ __launch_bounds__(256)
void policy_kernel(const float* __restrict__ A1T,
                   const float* __restrict__ PW0, const float* __restrict__ Pb0,
                   const float* __restrict__ PW1, const float* __restrict__ Pb1,
                   const float* __restrict__ PW2, const float* __restrict__ Pb2,
                   float* __restrict__ out)
{
    const int b = blockIdx.x * blockDim.x + threadIdx.x;
    if (b >= B_TOTAL) return;
    float hp[HID];
#pragma unroll
    for (int j = 0; j < HID; ++j) hp[j] = Pb0[j];
    for (int u = 0; u < U_UNITS; ++u) {
        const float v = A1T[(size_t)u * B_TOTAL + b];
#pragma unroll
        for (int j = 0; j < HID; ++j) hp[j] += v * PW0[j * U_UNITS + u];
    }
    float h[HID];
#pragma unroll
    for (int j = 0; j < HID; ++j) h[j] = fmaxf(hp[j], 0.f);
    float h2[HID];
#pragma unroll
    for (int g = 0; g < HID; ++g) {
        float s = Pb1[g];
#pragma unroll
        for (int j = 0; j < HID; ++j) s += h[j] * PW1[g * 8 + j];
        h2[g] = fmaxf(s, 0.f);
    }
    float o = Pb2[0];
#pragma unroll
    for (int j = 0; j < HID; ++j) o += h2[j] * PW2[j];
    out[b] = o;
}

// ============================================================================

extern "C" void kernel_launch(void* const* d_in, const int* in_sizes, int n_in,
                              void* d_out, int out_size, void* d_ws, size_t ws_size,
                              hipStream_t stream)
{
    const float* state = (const float*)d_in[0];
    const float* W0_0  = (const float*)d_in[1];
    const float* b0_0  = (const float*)d_in[2];
    const float* W1_0  = (const float*)d_in[3];
    const float* b1_0  = (const float*)d_in[4];
    const float* W2_0  = (const float*)d_in[5];
    const float* b2_0  = (const float*)d_in[6];
    const float* W0_1  = (const float*)d_in[7];
    const float* b0_1  = (const float*)d_in[8];
    const float* W1_1  = (const float*)d_in[9];
    const float* b1_1  = (const float*)d_in[10];
    const float* W2_1  = (const float*)d_in[11];
    const float* b2_1  = (const float*)d_in[12];
    const float* PW0   = (const float*)d_in[13];
    const float* Pb0   = (const float*)d_in[14];
    const float* PW1   = (const float*)d_in[15];
    const float* Pb1   = (const float*)d_in[16];
    const float* PW2   = (const float*)d_in[17];
    const float* Pb2   = (const float*)d_in[18];

    // ws layout (bytes)
    const size_t SZ_STATE = (size_t)B_TOTAL * F_IN;        // elems
    const size_t SZ_W00   = (size_t)U_UNITS * HID * F_IN;
    const size_t SZ_W01   = (size_t)U_UNITS * HID * U_UNITS;
    const size_t NEED = (2 * SZ_STATE + 2 * SZ_W00 + 2 * SZ_W01
                         + (size_t)B_TOTAL * U_UNITS) * 2            // fp16 parts + a0
                        + (size_t)U_UNITS * B_TOTAL * 4;             // a1T fp32

    if (ws_size >= NEED) {
        char* p = (char*)d_ws;
        _Float16* state_h = (_Float16*)p;                p += SZ_STATE * 2;
        _Float16* state_l = (_Float16*)p;                p += SZ_STATE * 2;
        _Float16* w00_h   = (_Float16*)p;                p += SZ_W00 * 2;
        _Float16* w00_l   = (_Float16*)p;                p += SZ_W00 * 2;
        _Float16* w01_h   = (_Float16*)p;                p += SZ_W01 * 2;
        _Float16* w01_l   = (_Float16*)p;                p += SZ_W01 * 2;
        _Float16* a0      = (_Float16*)p;                p += (size_t)B_TOTAL * U_UNITS * 2;
        float*    a1T     = (float*)p;

        split2_kernel<<<(int)(SZ_STATE / 4 + 255) / 256, 256, 0, stream>>>(state, state_h, state_l, (int)(SZ_STATE / 4));
        split2_kernel<<<(int)(SZ_W00 / 4 + 255) / 256, 256, 0, stream>>>(W0_0, w00_h, w00_l, (int)(SZ_W00 / 4));
        split2_kernel<<<(int)(SZ_W01 / 4 + 255) / 256, 256, 0, stream>>>(W0_1, w01_h, w01_l, (int)(SZ_W01 / 4));

        dim3 grid((U_UNITS * HID) / BN, B_TOTAL / BM);   // (16, 64)

        coagent_mfma<F_IN, true, false><<<grid, 256, 0, stream>>>(
            state_h, state_l, w00_h, w00_l, b0_0, W1_0, b1_0, W2_0, b2_0, (void*)a0);

        coagent_mfma<U_UNITS, false, true><<<grid, 256, 0, stream>>>(
            a0, nullptr, w01_h, w01_l, b0_1, W1_1, b1_1, W2_1, b2_1, (void*)a1T);

        policy_kernel<<<B_TOTAL / 256, 256, 0, stream>>>(
            a1T, PW0, Pb0, PW1, Pb1, PW2, Pb2, (float*)d_out);
    } else {
        // fp32 fallback (round-1 path, needs 16 MB ws)
        float* a0T = (float*)d_ws;
        float* a1T = a0T + (size_t)U_UNITS * B_TOTAL;
        dim3 grid((U_UNITS * HID) / FBN, B_TOTAL / FBM);
        coagent_kernel<F_IN, false><<<grid, 256, 0, stream>>>(
            state, W0_0, b0_0, W1_0, b1_0, W2_0, b2_0, a0T);
        coagent_kernel<U_UNITS, true><<<grid, 256, 0, stream>>>(
            a0T, W0_1, b0_1, W1_1, b1_1, W2_1, b2_1, a1T);
        policy_kernel<<<B_TOTAL / 256, 256, 0, stream>>>(
            a1T, PW0, Pb0, PW1, Pb1, PW2, Pb2, (float*)d_out);
    }
}

// Round 5
// 401.570 us; speedup vs baseline: 3.7353x; 1.0970x over previous
//
#include <hip/hip_runtime.h>
#include <cstring>
#include <cstdint>

// Problem constants (fixed by reference)
#define B_TOTAL 8192
#define F_IN    1024
#define U_UNITS 256
#define NACT    16
#define HID     8

typedef float    f32x4  __attribute__((ext_vector_type(4)));
typedef _Float16 half8  __attribute__((ext_vector_type(8)));
typedef _Float16 half4  __attribute__((ext_vector_type(4)));

#define GLOBAL_AS __attribute__((address_space(1)))
#define LDS_AS    __attribute__((address_space(3)))

// ============================================================================
// MFMA path: fp16 split-2 emulation of fp32 GEMM (3 passes; 2 when A exact).
// Low parts pre-scaled by 2048 (fp16 normal range; unscaled lows are subnormal
// -> flushed -> argmax flips, R2's failure). Cross terms in acc2 @ 2^-11.
//
// R5: operands PRE-PACKED in fragment order [rowtile][ktile][lane][8]halves so
// every __builtin_amdgcn_global_load_lds is lane-contiguous (base + lane*16B)
// -- the m97-verified fast DMA pattern. R4's row-major gather put consecutive
// lanes 2KB apart (16 cache lines per instr) and stayed latency-bound at
// MfmaUtil 18%. MFMA values/order bit-identical to R3/R4 => absmax unchanged.
// ============================================================================

// src [R][K] fp32 -> packed high/low fp16: [R/16][K/32][64][8] halves
// lane = ((k>>3)&3)*16 + (r&15), pos = k&7  (fragment order for 16x16x32)
template<bool SPLIT>
__global__ __launch_bounds__(256)
void pack_kernel(const float* __restrict__ src, _Float16* __restrict__ dh,
                 _Float16* __restrict__ dl, int K)
{
    __shared__ float ls[16 * 132];         // 16 rows x 128 cols, +4 pad
    const int tid = threadIdx.x;
    const int nkb = K >> 7;                // 128-col slabs per row
    const int mt  = blockIdx.x / nkb;      // 16-row tile
    const int kb  = blockIdx.x % nkb;      // 128-col slab
    const int r0  = mt * 16;

    // coalesced read: 16 rows x 128 fp32 (2048 fp32, two float4 per thread)
#pragma unroll
    for (int i = 0; i < 2; ++i) {
        const int e = tid + (i << 8);      // float4 index 0..511
        const int row = e >> 5;            // 32 float4 per row
        const int c4  = e & 31;
        f32x4 v = *reinterpret_cast<const f32x4*>(
            &src[(size_t)(r0 + row) * K + (kb << 7) + (c4 << 2)]);
        *reinterpret_cast<f32x4*>(&ls[row * 132 + (c4 << 2)]) = v;
    }
    __syncthreads();

    // packed write: thread t -> k-octet k8 = t>>4, row r = t&15
    const int k8 = tid >> 4, r = tid & 15;
    float x[8];
#pragma unroll
    for (int j = 0; j < 8; ++j) x[j] = ls[r * 132 + (k8 << 3) + j];
    half8 h, l;
#pragma unroll
    for (int j = 0; j < 8; ++j) {
        h[j] = (_Float16)x[j];
        l[j] = (_Float16)((x[j] - (float)h[j]) * 2048.0f);
    }
    // ktile = kb*4 + (k8>>2), lane = (k8&3)*16 + r -> sequential 16B chunks
    const size_t off = (((size_t)mt * (K >> 5)) + (kb << 2) + (k8 >> 2)) * 512
                     + (size_t)(((k8 & 3) << 4) + r) * 8;
    *reinterpret_cast<half8*>(&dh[off]) = h;
    if (SPLIT) *reinterpret_cast<half8*>(&dl[off]) = l;
}

constexpr int BM = 128, BN = 128, BK = 32;

// h_pre = X @ W^T via fp16-split MFMA, fused per-unit MLP (+b0,relu,8x8,relu,
// 16x8,argmax) epilogue. All operands in packed fragment layout.
//  A_SPLIT:   X has a (scaled) low part (layer 0). Else X exact fp16 (layer 1).
//  OUT_TF32:  write fp32 transposed [U][B] (layer 1 -> policy head);
//             else write a0 in PACKED fp16 layout (feeds layer 1's A, NTK=8).
template<int K_TOTAL, bool A_SPLIT, bool OUT_TF32>
__global__ __launch_bounds__(256, 2)
void coagent_mfma(const _Float16* __restrict__ Ahg, const _Float16* __restrict__ Alg,
                  const _Float16* __restrict__ Bhg, const _Float16* __restrict__ Blg,
                  const float* __restrict__ b0, const float* __restrict__ W1,
                  const float* __restrict__ b1, const float* __restrict__ W2,
                  const float* __restrict__ b2, void* __restrict__ outp)
{
    // parts: 0=Ah 1=Al 2=Bh 3=Bl ; tile = 16 rows ; 64 lanes x 8 halves
    struct GemmBufs { _Float16 t[4][8][512]; };
    struct EpiBufs  { float Hs[BM][65]; _Float16 ab[BM * 8]; };
    union SMem { GemmBufs g; EpiBufs e; };
    __shared__ SMem sm;

    constexpr int NTK = K_TOTAL >> 5;    // k-tiles per row-tile

    const int tid  = threadIdx.x;
    const int wave = tid >> 6;
    const int lane = tid & 63;
    const int quad = lane >> 4;
    const int l15  = lane & 15;
    const int wm   = (wave >> 1) * 64;   // wave tile 64x64
    const int m0   = blockIdx.y * BM;
    const int n0   = blockIdx.x * BN;

    // ---- per-wave staging descriptors: lane-contiguous 1KB chunks ----
    constexpr int NL = A_SPLIT ? 8 : 6;
    const _Float16* gsrc[NL];
    _Float16*       ldst[NL];
#pragma unroll
    for (int j = 0; j < NL; ++j) {
        int part, tile;
        if (A_SPLIT) { part = wave; tile = j; }          // 4 parts x 8 tiles
        else { const int q = j * 4 + wave; part = q >> 3; tile = q & 7; } // 3 parts
        const int phys = A_SPLIT ? part : (part == 0 ? 0 : part + 1);
        const bool isA = (phys <= 1);
        const _Float16* src = (phys == 0) ? Ahg : (phys == 1) ? Alg
                            : (phys == 2) ? Bhg : Blg;
        const int rt = ((isA ? m0 : n0) >> 4) + tile;
        gsrc[j] = src + (size_t)rt * NTK * 512 + lane * 8;   // + kt*512 later
        ldst[j] = &sm.g.t[phys][tile][0];
    }

    f32x4 acc1[4][4];   // Ah*Bh            (scale 1)
    f32x4 acc2[4][4];   // Al'*Bh + Ah*Bl'  (scale 2^-11)
#pragma unroll
    for (int i = 0; i < 4; ++i)
#pragma unroll
        for (int j = 0; j < 4; ++j) { acc1[i][j] = {0.f,0.f,0.f,0.f}; acc2[i][j] = {0.f,0.f,0.f,0.f}; }

    const int at = (wave >> 1) * 4;   // this wave's A tiles
    const int bt = (wave & 1) * 4;    // this wave's B tiles

    for (int kt = 0; kt < NTK; ++kt) {
        __syncthreads();   // previous iter's fragments consumed
#pragma unroll
        for (int j = 0; j < NL; ++j) {
            __builtin_amdgcn_global_load_lds(
                (const GLOBAL_AS void*)(gsrc[j] + (size_t)kt * 512),
                (LDS_AS void*)ldst[j], 16, 0, 0);
        }
        __syncthreads();   // vmcnt drained before barrier

        half8 af[4], bf[4], xf[4];
#pragma unroll
        for (int mt = 0; mt < 4; ++mt)
            af[mt] = *reinterpret_cast<const half8*>(&sm.g.t[0][at + mt][lane * 8]);
#pragma unroll
        for (int nt = 0; nt < 4; ++nt)
            bf[nt] = *reinterpret_cast<const half8*>(&sm.g.t[2][bt + nt][lane * 8]);
#pragma unroll
        for (int mt = 0; mt < 4; ++mt)
#pragma unroll
            for (int nt = 0; nt < 4; ++nt)
                acc1[mt][nt] = __builtin_amdgcn_mfma_f32_16x16x32_f16(af[mt], bf[nt], acc1[mt][nt], 0, 0, 0);
        if (A_SPLIT) {
#pragma unroll
            for (int mt = 0; mt < 4; ++mt)
                xf[mt] = *reinterpret_cast<const half8*>(&sm.g.t[1][at + mt][lane * 8]);
#pragma unroll
            for (int mt = 0; mt < 4; ++mt)
#pragma unroll
                for (int nt = 0; nt < 4; ++nt)
                    acc2[mt][nt] = __builtin_amdgcn_mfma_f32_16x16x32_f16(xf[mt], bf[nt], acc2[mt][nt], 0, 0, 0);
        }
#pragma unroll
        for (int nt = 0; nt < 4; ++nt)
            xf[nt] = *reinterpret_cast<const half8*>(&sm.g.t[3][bt + nt][lane * 8]);
#pragma unroll
        for (int mt = 0; mt < 4; ++mt)
#pragma unroll
            for (int nt = 0; nt < 4; ++nt)
                acc2[mt][nt] = __builtin_amdgcn_mfma_f32_16x16x32_f16(af[mt], xf[nt], acc2[mt][nt], 0, 0, 0);
    }

    // ---- epilogue: two 64-col halves (8 units each) ----
    const int ubase = n0 >> 3;
    for (int half = 0; half < 2; ++half) {
        __syncthreads();
        if ((wave & 1) == half) {        // 2 waves own these 64 cols
#pragma unroll
            for (int mt = 0; mt < 4; ++mt)
#pragma unroll
                for (int nt = 0; nt < 4; ++nt)
#pragma unroll
                    for (int r = 0; r < 4; ++r)
                        sm.e.Hs[wm + mt * 16 + quad * 4 + r][nt * 16 + l15] =
                            acc1[mt][nt][r] + acc2[mt][nt][r] * (1.0f / 2048.0f);
        }
        __syncthreads();
#pragma unroll
        for (int p = 0; p < 4; ++p) {
            const int pair = (p << 8) + tid;
            const int ul = pair >> 7;           // wave-uniform
            const int bl = pair & 127;          // lane-consecutive
            const int u  = ubase + half * 8 + ul;

            float h[HID];
#pragma unroll
            for (int j = 0; j < HID; ++j)
                h[j] = fmaxf(sm.e.Hs[bl][ul * 8 + j] + b0[u * 8 + j], 0.f);

            float h2[HID];
#pragma unroll
            for (int g = 0; g < HID; ++g) {
                float s = b1[u * 8 + g];
#pragma unroll
                for (int j = 0; j < HID; ++j)
                    s += h[j] * W1[u * 64 + g * 8 + j];
                h2[g] = fmaxf(s, 0.f);
            }

            float best = b2[u * 16];
#pragma unroll
            for (int j = 0; j < HID; ++j) best += h2[j] * W2[u * 128 + j];
            int bi = 0;
#pragma unroll
            for (int a = 1; a < NACT; ++a) {
                float s = b2[u * 16 + a];
#pragma unroll
                for (int j = 0; j < HID; ++j)
                    s += h2[j] * W2[u * 128 + a * 8 + j];
                if (s > best) { best = s; bi = a; }   // first-max-wins = np.argmax
            }

            if (OUT_TF32) {
                ((float*)outp)[(size_t)u * B_TOTAL + m0 + bl] = (float)bi;
            } else {
                sm.e.ab[bl * 8 + ul] = (_Float16)bi;
            }
        }
        if (!OUT_TF32) {
            __syncthreads();
            if (tid < 128) {   // write a0 in PACKED layout (NTK=8 for K=256)
                float4 v = *reinterpret_cast<float4*>(&sm.e.ab[tid * 8]);
                const int u = ubase + half * 8;          // octet base, uniform
                const int b = m0 + tid;
                const size_t off = ((size_t)(b >> 4) * 8 + (u >> 5)) * 512
                                 + (size_t)((((u >> 3) & 3) << 4) + (b & 15)) * 8;
                *reinterpret_cast<float4*>(&((_Float16*)outp)[off]) = v;
            }
        }
    }
}

// ============================================================================
// fp32 fallback path (round-1 kernels) — used only if ws_size is too small
// ============================================================================

constexpr int FBM = 128, FBN = 128, FBK = 16;

template<int K_TOTAL, bool X_TRANSPOSED>
__global__ __launch_bounds__(256, 2)
void coagent_kernel(const float* __restrict__ X, const float* __restrict__ W0,
                    const float* __restrict__ b0, const float* __restrict__ W1,
                    const float* __restrict__ b1, const float* __restrict__ W2,
                    const float* __restrict__ b2, float* __restrict__ outT)
{
    struct SMemGemm { float As[FBK][FBM + 4]; float Bs[FBK][FBN + 4]; };
    union SMem { SMemGemm g; float Hs[FBM][65]; };
    __shared__ SMem sm;

    const int tid = threadIdx.x;
    const int tx = tid & 15, ty = tid >> 4;
    const int m0 = blockIdx.y * FBM, n0 = blockIdx.x * FBN;

    float acc[8][8];
#pragma unroll
    for (int i = 0; i < 8; ++i)
#pragma unroll
        for (int j = 0; j < 8; ++j) acc[i][j] = 0.f;

    for (int k0 = 0; k0 < K_TOTAL; k0 += FBK) {
        __syncthreads();
        if (X_TRANSPOSED) {
#pragma unroll
            for (int l = tid; l < (FBM * FBK) / 4; l += 256) {
                const int k = l >> 5, q = l & 31;
                const float4 v = *reinterpret_cast<const float4*>(
                    &X[(size_t)(k0 + k) * B_TOTAL + m0 + 4 * q]);
                *reinterpret_cast<float4*>(&sm.g.As[k][4 * q]) = v;
            }
        } else {
#pragma unroll
            for (int l = tid; l < (FBM * FBK) / 4; l += 256) {
                const int row = l >> 2, c = l & 3;
                const float4 v = *reinterpret_cast<const float4*>(
                    &X[(size_t)(m0 + row) * K_TOTAL + k0 + 4 * c]);
                sm.g.As[4 * c + 0][row] = v.x; sm.g.As[4 * c + 1][row] = v.y;
                sm.g.As[4 * c + 2][row] = v.z; sm.g.As[4 * c + 3][row] = v.w;
            }
        }
#pragma unroll
        for (int l = tid; l < (FBN * FBK) / 4; l += 256) {
            const int row = l >> 2, c = l & 3;
            const float4 v = *reinterpret_cast<const float4*>(
                &W0[(size_t)(n0 + row) * K_TOTAL + k0 + 4 * c]);
            sm.g.Bs[4 * c + 0][row] = v.x; sm.g.Bs[4 * c + 1][row] = v.y;
            sm.g.Bs[4 * c + 2][row] = v.z; sm.g.Bs[4 * c + 3][row] = v.w;
        }
        __syncthreads();
#pragma unroll
        for (int k = 0; k < FBK; ++k) {
            float a[8], bb[8];
            *reinterpret_cast<float4*>(&a[0])  = *reinterpret_cast<float4*>(&sm.g.As[k][4 * ty]);
            *reinterpret_cast<float4*>(&a[4])  = *reinterpret_cast<float4*>(&sm.g.As[k][64 + 4 * ty]);
            *reinterpret_cast<float4*>(&bb[0]) = *reinterpret_cast<float4*>(&sm.g.Bs[k][4 * tx]);
            *reinterpret_cast<float4*>(&bb[4]) = *reinterpret_cast<float4*>(&sm.g.Bs[k][64 + 4 * tx]);
#pragma unroll
            for (int i = 0; i < 8; ++i)
#pragma unroll
                for (int j = 0; j < 8; ++j) acc[i][j] += a[i] * bb[j];
        }
    }

    const int ub_base = n0 >> 3;
    for (int half = 0; half < 2; ++half) {
        __syncthreads();
#pragma unroll
        for (int i = 0; i < 8; ++i) {
            const int row = (i < 4) ? (4 * ty + i) : (64 + 4 * ty + (i - 4));
#pragma unroll
            for (int j = 0; j < 4; ++j)
                sm.Hs[row][4 * tx + j] = acc[i][4 * half + j];
        }
        __syncthreads();
#pragma unroll
        for (int p = 0; p < 4; ++p) {
            const int pair = (p << 8) + tid;
            const int ul = pair >> 7, bl = pair & 127;
            const int u = ub_base + half * 8 + ul;
            float h[HID];
#pragma unroll
            for (int j = 0; j < HID; ++j)
                h[j] = fmaxf(sm.Hs[bl][ul * 8 + j] + b0[u * 8 + j], 0.f);
            float h2[HID];
#pragma unroll
            for (int g = 0; g < HID; ++g) {
                float s = b1[u * 8 + g];
#pragma unroll
                for (int j = 0; j < HID; ++j) s += h[j] * W1[u * 64 + g * 8 + j];
                h2[g] = fmaxf(s, 0.f);
            }
            float best = b2[u * 16];
#pragma unroll
            for (int j = 0; j < HID; ++j) best += h2[j] * W2[u * 128 + j];
            int bi = 0;
#pragma unroll
            for (int a = 1; a < NACT; ++a) {
                float s = b2[u * 16 + a];
#pragma unroll
                for (int j = 0; j < HID; ++j) s += h2[j] * W2[u * 128 + a * 8 + j];
                if (s > best) { best = s; bi = a; }
            }
            outT[(size_t)u * B_TOTAL + m0 + bl] = (float)bi;
        }
    }
}

// Policy head (reads a1T fp32 [U][B], coalesced across lanes)
__global__ __launch_bounds__(256)
void policy_kernel(const float* __restrict__ A1T,
                   const float* __restrict__ PW0, const float* __restrict__ Pb0,
                   const float* __restrict__ PW1, const float* __restrict__ Pb1,
                   const float* __restrict__ PW2, const float* __restrict__ Pb2,
                   float* __restrict__ out)
{
    const int b = blockIdx.x * blockDim.x + threadIdx.x;
    if (b >= B_TOTAL) return;
    float hp[HID];
#pragma unroll
    for (int j = 0; j < HID; ++j) hp[j] = Pb0[j];
    for (int u = 0; u < U_UNITS; ++u) {
        const float v = A1T[(size_t)u * B_TOTAL + b];
#pragma unroll
        for (int j = 0; j < HID; ++j) hp[j] += v * PW0[j * U_UNITS + u];
    }
    float h[HID];
#pragma unroll
    for (int j = 0; j < HID; ++j) h[j] = fmaxf(hp[j], 0.f);
    float h2[HID];
#pragma unroll
    for (int g = 0; g < HID; ++g) {
        float s = Pb1[g];
#pragma unroll
        for (int j = 0; j < HID; ++j) s += h[j] * PW1[g * 8 + j];
        h2[g] = fmaxf(s, 0.f);
    }
    float o = Pb2[0];
#pragma unroll
    for (int j = 0; j < HID; ++j) o += h2[j] * PW2[j];
    out[b] = o;
}

// ============================================================================

extern "C" void kernel_launch(void* const* d_in, const int* in_sizes, int n_in,
                              void* d_out, int out_size, void* d_ws, size_t ws_size,
                              hipStream_t stream)
{
    const float* state = (const float*)d_in[0];
    const float* W0_0  = (const float*)d_in[1];
    const float* b0_0  = (const float*)d_in[2];
    const float* W1_0  = (const float*)d_in[3];
    const float* b1_0  = (const float*)d_in[4];
    const float* W2_0  = (const float*)d_in[5];
    const float* b2_0  = (const float*)d_in[6];
    const float* W0_1  = (const float*)d_in[7];
    const float* b0_1  = (const float*)d_in[8];
    const float* W1_1  = (const float*)d_in[9];
    const float* b1_1  = (const float*)d_in[10];
    const float* W2_1  = (const float*)d_in[11];
    const float* b2_1  = (const float*)d_in[12];
    const float* PW0   = (const float*)d_in[13];
    const float* Pb0   = (const float*)d_in[14];
    const float* PW1   = (const float*)d_in[15];
    const float* Pb1   = (const float*)d_in[16];
    const float* PW2   = (const float*)d_in[17];
    const float* Pb2   = (const float*)d_in[18];

    // ws layout (elements)
    const size_t SZ_STATE = (size_t)B_TOTAL * F_IN;
    const size_t SZ_W00   = (size_t)U_UNITS * HID * F_IN;
    const size_t SZ_W01   = (size_t)U_UNITS * HID * U_UNITS;
    const size_t NEED = (2 * SZ_STATE + 2 * SZ_W00 + 2 * SZ_W01
                         + (size_t)B_TOTAL * U_UNITS) * 2            // fp16 parts + a0
                        + (size_t)U_UNITS * B_TOTAL * 4;             // a1T fp32

    if (ws_size >= NEED) {
        char* p = (char*)d_ws;
        _Float16* state_h = (_Float16*)p;                p += SZ_STATE * 2;
        _Float16* state_l = (_Float16*)p;                p += SZ_STATE * 2;
        _Float16* w00_h   = (_Float16*)p;                p += SZ_W00 * 2;
        _Float16* w00_l   = (_Float16*)p;                p += SZ_W00 * 2;
        _Float16* w01_h   = (_Float16*)p;                p += SZ_W01 * 2;
        _Float16* w01_l   = (_Float16*)p;                p += SZ_W01 * 2;
        _Float16* a0      = (_Float16*)p;                p += (size_t)B_TOTAL * U_UNITS * 2;
        float*    a1T     = (float*)p;

        // pack fp32 -> fragment-ordered fp16 (h, l*2048)
        pack_kernel<true><<<(B_TOTAL / 16) * (F_IN / 128), 256, 0, stream>>>(
            state, state_h, state_l, F_IN);
        pack_kernel<true><<<(U_UNITS * HID / 16) * (F_IN / 128), 256, 0, stream>>>(
            W0_0, w00_h, w00_l, F_IN);
        pack_kernel<true><<<(U_UNITS * HID / 16) * (U_UNITS / 128), 256, 0, stream>>>(
            W0_1, w01_h, w01_l, U_UNITS);

        dim3 grid((U_UNITS * HID) / BN, B_TOTAL / BM);   // (16, 64)

        coagent_mfma<F_IN, true, false><<<grid, 256, 0, stream>>>(
            state_h, state_l, w00_h, w00_l, b0_0, W1_0, b1_0, W2_0, b2_0, (void*)a0);

        coagent_mfma<U_UNITS, false, true><<<grid, 256, 0, stream>>>(
            a0, nullptr, w01_h, w01_l, b0_1, W1_1, b1_1, W2_1, b2_1, (void*)a1T);

        policy_kernel<<<B_TOTAL / 256, 256, 0, stream>>>(
            a1T, PW0, Pb0, PW1, Pb1, PW2, Pb2, (float*)d_out);
    } else {
        // fp32 fallback (round-1 path, needs 16 MB ws)
        float* a0T = (float*)d_ws;
        float* a1T = a0T + (size_t)U_UNITS * B_TOTAL;
        dim3 grid((U_UNITS * HID) / FBN, B_TOTAL / FBM);
        coagent_kernel<F_IN, false><<<grid, 256, 0, stream>>>(
            state, W0_0, b0_0, W1_0, b1_0, W2_0, b2_0, a0T);
        coagent_kernel<U_UNITS, true><<<grid, 256, 0, stream>>>(
            a0T, W0_1, b0_1, W1_1, b1_1, W2_1, b2_1, a1T);
        policy_kernel<<<B_TOTAL / 256, 256, 0, stream>>>(
            a1T, PW0, Pb0, PW1, Pb1, PW2, Pb2, (float*)d_out);
    }
}

// Round 6
// 358.227 us; speedup vs baseline: 4.1872x; 1.1210x over previous
//
#include <hip/hip_runtime.h>
#include <cstring>
#include <cstdint>

// Problem constants (fixed by reference)
#define B_TOTAL 8192
#define F_IN    1024
#define U_UNITS 256
#define NACT    16
#define HID     8

typedef float    f32x4  __attribute__((ext_vector_type(4)));
typedef _Float16 half8  __attribute__((ext_vector_type(8)));
typedef _Float16 half4  __attribute__((ext_vector_type(4)));

// ============================================================================
// MFMA path: fp16 split-2 emulation of fp32 GEMM (3 passes; 2 when A exact).
// Low parts pre-scaled by 2048 (fp16 normal range; unscaled lows are subnormal
// -> flushed -> argmax flips, R2's failure). Cross terms in acc2 @ 2^-11.
//
// R6: NO LDS / NO BARRIERS in the K-loop. Operands are pre-packed in exact
// fragment order [rowtile][ktile][lane][8]halves, so each wave loads its MFMA
// fragments straight from global into VGPRs (global_load_dwordx4 at
// base + lane*16B, 1KB coalesced per instr, L1/L2-served). R5's per-kt
// DMA->vmcnt(0)->barrier->ds_read chain was the wall (MfmaUtil 21% with both
// LDS BW and MFMA pipes underused); waves now pipeline independently.
// MFMA values/order bit-identical to R3..R5 => absmax unchanged (0.21875).
// ============================================================================

// src [R][K] fp32 -> packed high/low fp16: [R/16][K/32][64][8] halves
// lane = ((k>>3)&3)*16 + (r&15), pos = k&7  (fragment order for 16x16x32)
template<bool SPLIT>
__global__ __launch_bounds__(256)
void pack_kernel(const float* __restrict__ src, _Float16* __restrict__ dh,
                 _Float16* __restrict__ dl, int K)
{
    __shared__ float ls[16 * 132];         // 16 rows x 128 cols, +4 pad
    const int tid = threadIdx.x;
    const int nkb = K >> 7;                // 128-col slabs per row
    const int mt  = blockIdx.x / nkb;      // 16-row tile
    const int kb  = blockIdx.x % nkb;      // 128-col slab
    const int r0  = mt * 16;

    // coalesced read: 16 rows x 128 fp32 (2048 fp32, two float4 per thread)
#pragma unroll
    for (int i = 0; i < 2; ++i) {
        const int e = tid + (i << 8);      // float4 index 0..511
        const int row = e >> 5;            // 32 float4 per row
        const int c4  = e & 31;
        f32x4 v = *reinterpret_cast<const f32x4*>(
            &src[(size_t)(r0 + row) * K + (kb << 7) + (c4 << 2)]);
        *reinterpret_cast<f32x4*>(&ls[row * 132 + (c4 << 2)]) = v;
    }
    __syncthreads();

    // packed write: thread t -> k-octet k8 = t>>4, row r = t&15
    const int k8 = tid >> 4, r = tid & 15;
    float x[8];
#pragma unroll
    for (int j = 0; j < 8; ++j) x[j] = ls[r * 132 + (k8 << 3) + j];
    half8 h, l;
#pragma unroll
    for (int j = 0; j < 8; ++j) {
        h[j] = (_Float16)x[j];
        l[j] = (_Float16)((x[j] - (float)h[j]) * 2048.0f);
    }
    // ktile = kb*4 + (k8>>2), lane = (k8&3)*16 + r -> sequential 16B chunks
    const size_t off = (((size_t)mt * (K >> 5)) + (kb << 2) + (k8 >> 2)) * 512
                     + (size_t)(((k8 & 3) << 4) + r) * 8;
    *reinterpret_cast<half8*>(&dh[off]) = h;
    if (SPLIT) *reinterpret_cast<half8*>(&dl[off]) = l;
}

constexpr int BM = 128, BN = 128;

// h_pre = X @ W^T via fp16-split MFMA, fused per-unit MLP (+b0,relu,8x8,relu,
// 16x8,argmax) epilogue. All operands in packed fragment layout; fragments
// loaded global->VGPR directly (no LDS in K-loop).
//  A_SPLIT:   X has a (scaled) low part (layer 0). Else X exact fp16 (layer 1).
//  OUT_TF32:  write fp32 transposed [U][B] (layer 1 -> policy head);
//             else write a0 in PACKED fp16 layout (feeds layer 1's A, NTK=8).
template<int K_TOTAL, bool A_SPLIT, bool OUT_TF32>
__global__ __launch_bounds__(256, 2)
void coagent_mfma(const _Float16* __restrict__ Ahg, const _Float16* __restrict__ Alg,
                  const _Float16* __restrict__ Bhg, const _Float16* __restrict__ Blg,
                  const float* __restrict__ b0, const float* __restrict__ W1,
                  const float* __restrict__ b1, const float* __restrict__ W2,
                  const float* __restrict__ b2, void* __restrict__ outp)
{
    struct EpiBufs { float Hs[BM][65]; _Float16 ab[BM * 8]; };
    __shared__ EpiBufs sm;

    constexpr int NTK = K_TOTAL >> 5;        // k-tiles (K=32 each)
    constexpr size_t TS = (size_t)NTK * 512; // halves per row-tile

    const int tid  = threadIdx.x;
    const int wave = tid >> 6;
    const int lane = tid & 63;
    const int quad = lane >> 4;
    const int l15  = lane & 15;
    const int wm   = (wave >> 1) * 64;   // wave tile 64x64
    const int m0   = blockIdx.y * BM;
    const int n0   = blockIdx.x * BN;

    const int at = (wave >> 1) * 4;      // this wave's A row-tiles
    const int bt = (wave & 1) * 4;       // this wave's B row-tiles

    // per-lane fragment base pointers (lane-contiguous 16B chunks)
    const _Float16* Ah0 = Ahg + ((size_t)((m0 >> 4) + at)) * TS + lane * 8;
    const _Float16* Al0 = A_SPLIT ? (Alg + ((size_t)((m0 >> 4) + at)) * TS + lane * 8) : nullptr;
    const _Float16* Bh0 = Bhg + ((size_t)((n0 >> 4) + bt)) * TS + lane * 8;
    const _Float16* Bl0 = Blg + ((size_t)((n0 >> 4) + bt)) * TS + lane * 8;

    f32x4 acc1[4][4];   // Ah*Bh            (scale 1)
    f32x4 acc2[4][4];   // Al'*Bh + Ah*Bl'  (scale 2^-11)
#pragma unroll
    for (int i = 0; i < 4; ++i)
#pragma unroll
        for (int j = 0; j < 4; ++j) { acc1[i][j] = {0.f,0.f,0.f,0.f}; acc2[i][j] = {0.f,0.f,0.f,0.f}; }

    for (int kt = 0; kt < NTK; ++kt) {
        const size_t ko = (size_t)kt * 512;
        half8 af[4], bf[4], xa[4], xb[4];
        // issue all fragment loads up front (highs first: pass-1 can start
        // as soon as af/bf arrive; lows still in flight)
#pragma unroll
        for (int mt = 0; mt < 4; ++mt)
            af[mt] = *reinterpret_cast<const half8*>(Ah0 + mt * TS + ko);
#pragma unroll
        for (int nt = 0; nt < 4; ++nt)
            bf[nt] = *reinterpret_cast<const half8*>(Bh0 + nt * TS + ko);
        if (A_SPLIT) {
#pragma unroll
            for (int mt = 0; mt < 4; ++mt)
                xa[mt] = *reinterpret_cast<const half8*>(Al0 + mt * TS + ko);
        }
#pragma unroll
        for (int nt = 0; nt < 4; ++nt)
            xb[nt] = *reinterpret_cast<const half8*>(Bl0 + nt * TS + ko);

        // pass 1: Ah*Bh -> acc1
#pragma unroll
        for (int mt = 0; mt < 4; ++mt)
#pragma unroll
            for (int nt = 0; nt < 4; ++nt)
                acc1[mt][nt] = __builtin_amdgcn_mfma_f32_16x16x32_f16(af[mt], bf[nt], acc1[mt][nt], 0, 0, 0);
        // pass 2: Al'*Bh -> acc2
        if (A_SPLIT) {
#pragma unroll
            for (int mt = 0; mt < 4; ++mt)
#pragma unroll
                for (int nt = 0; nt < 4; ++nt)
                    acc2[mt][nt] = __builtin_amdgcn_mfma_f32_16x16x32_f16(xa[mt], bf[nt], acc2[mt][nt], 0, 0, 0);
        }
        // pass 3: Ah*Bl' -> acc2
#pragma unroll
        for (int mt = 0; mt < 4; ++mt)
#pragma unroll
            for (int nt = 0; nt < 4; ++nt)
                acc2[mt][nt] = __builtin_amdgcn_mfma_f32_16x16x32_f16(af[mt], xb[nt], acc2[mt][nt], 0, 0, 0);
    }

    // ---- epilogue: two 64-col halves (8 units each) ----
    const int ubase = n0 >> 3;
    for (int half = 0; half < 2; ++half) {
        __syncthreads();
        if ((wave & 1) == half) {        // 2 waves own these 64 cols
#pragma unroll
            for (int mt = 0; mt < 4; ++mt)
#pragma unroll
                for (int nt = 0; nt < 4; ++nt)
#pragma unroll
                    for (int r = 0; r < 4; ++r)
                        sm.Hs[wm + mt * 16 + quad * 4 + r][nt * 16 + l15] =
                            acc1[mt][nt][r] + acc2[mt][nt][r] * (1.0f / 2048.0f);
        }
        __syncthreads();
#pragma unroll
        for (int p = 0; p < 4; ++p) {
            const int pair = (p << 8) + tid;
            const int ul = pair >> 7;           // wave-uniform
            const int bl = pair & 127;          // lane-consecutive
            const int u  = ubase + half * 8 + ul;

            float h[HID];
#pragma unroll
            for (int j = 0; j < HID; ++j)
                h[j] = fmaxf(sm.Hs[bl][ul * 8 + j] + b0[u * 8 + j], 0.f);

            float h2[HID];
#pragma unroll
            for (int g = 0; g < HID; ++g) {
                float s = b1[u * 8 + g];
#pragma unroll
                for (int j = 0; j < HID; ++j)
                    s += h[j] * W1[u * 64 + g * 8 + j];
                h2[g] = fmaxf(s, 0.f);
            }

            float best = b2[u * 16];
#pragma unroll
            for (int j = 0; j < HID; ++j) best += h2[j] * W2[u * 128 + j];
            int bi = 0;
#pragma unroll
            for (int a = 1; a < NACT; ++a) {
                float s = b2[u * 16 + a];
#pragma unroll
                for (int j = 0; j < HID; ++j)
                    s += h2[j] * W2[u * 128 + a * 8 + j];
                if (s > best) { best = s; bi = a; }   // first-max-wins = np.argmax
            }

            if (OUT_TF32) {
                ((float*)outp)[(size_t)u * B_TOTAL + m0 + bl] = (float)bi;
            } else {
                sm.ab[bl * 8 + ul] = (_Float16)bi;
            }
        }
        if (!OUT_TF32) {
            __syncthreads();
            if (tid < 128) {   // write a0 in PACKED layout (NTK=8 for K=256)
                float4 v = *reinterpret_cast<float4*>(&sm.ab[tid * 8]);
                const int u = ubase + half * 8;          // octet base, uniform
                const int b = m0 + tid;
                const size_t off = ((size_t)(b >> 4) * 8 + (u >> 5)) * 512
                                 + (size_t)((((u >> 3) & 3) << 4) + (b & 15)) * 8;
                *reinterpret_cast<float4*>(&((_Float16*)outp)[off]) = v;
            }
        }
    }
}

// ============================================================================
// fp32 fallback path (round-1 kernels) — used only if ws_size is too small
// ============================================================================

constexpr int FBM = 128, FBN = 128, FBK = 16;

template<int K_TOTAL, bool X_TRANSPOSED>
__global__ __launch_bounds__(256, 2)
void coagent_kernel(const float* __restrict__ X, const float* __restrict__ W0,
                    const float* __restrict__ b0, const float* __restrict__ W1,
                    const float* __restrict__ b1, const float* __restrict__ W2,
                    const float* __restrict__ b2, float* __restrict__ outT)
{
    struct SMemGemm { float As[FBK][FBM + 4]; float Bs[FBK][FBN + 4]; };
    union SMem { SMemGemm g; float Hs[FBM][65]; };
    __shared__ SMem sm;

    const int tid = threadIdx.x;
    const int tx = tid & 15, ty = tid >> 4;
    const int m0 = blockIdx.y * FBM, n0 = blockIdx.x * FBN;

    float acc[8][8];
#pragma unroll
    for (int i = 0; i < 8; ++i)
#pragma unroll
        for (int j = 0; j < 8; ++j) acc[i][j] = 0.f;

    for (int k0 = 0; k0 < K_TOTAL; k0 += FBK) {
        __syncthreads();
        if (X_TRANSPOSED) {
#pragma unroll
            for (int l = tid; l < (FBM * FBK) / 4; l += 256) {
                const int k = l >> 5, q = l & 31;
                const float4 v = *reinterpret_cast<const float4*>(
                    &X[(size_t)(k0 + k) * B_TOTAL + m0 + 4 * q]);
                *reinterpret_cast<float4*>(&sm.g.As[k][4 * q]) = v;
            }
        } else {
#pragma unroll
            for (int l = tid; l < (FBM * FBK) / 4; l += 256) {
                const int row = l >> 2, c = l & 3;
                const float4 v = *reinterpret_cast<const float4*>(
                    &X[(size_t)(m0 + row) * K_TOTAL + k0 + 4 * c]);
                sm.g.As[4 * c + 0][row] = v.x; sm.g.As[4 * c + 1][row] = v.y;
                sm.g.As[4 * c + 2][row] = v.z; sm.g.As[4 * c + 3][row] = v.w;
            }
        }
#pragma unroll
        for (int l = tid; l < (FBN * FBK) / 4; l += 256) {
            const int row = l >> 2, c = l & 3;
            const float4 v = *reinterpret_cast<const float4*>(
                &W0[(size_t)(n0 + row) * K_TOTAL + k0 + 4 * c]);
            sm.g.Bs[4 * c + 0][row] = v.x; sm.g.Bs[4 * c + 1][row] = v.y;
            sm.g.Bs[4 * c + 2][row] = v.z; sm.g.Bs[4 * c + 3][row] = v.w;
        }
        __syncthreads();
#pragma unroll
        for (int k = 0; k < FBK; ++k) {
            float a[8], bb[8];
            *reinterpret_cast<float4*>(&a[0])  = *reinterpret_cast<float4*>(&sm.g.As[k][4 * ty]);
            *reinterpret_cast<float4*>(&a[4])  = *reinterpret_cast<float4*>(&sm.g.As[k][64 + 4 * ty]);
            *reinterpret_cast<float4*>(&bb[0]) = *reinterpret_cast<float4*>(&sm.g.Bs[k][4 * tx]);
            *reinterpret_cast<float4*>(&bb[4]) = *reinterpret_cast<float4*>(&sm.g.Bs[k][64 + 4 * tx]);
#pragma unroll
            for (int i = 0; i < 8; ++i)
#pragma unroll
                for (int j = 0; j < 8; ++j) acc[i][j] += a[i] * bb[j];
        }
    }

    const int ub_base = n0 >> 3;
    for (int half = 0; half < 2; ++half) {
        __syncthreads();
#pragma unroll
        for (int i = 0; i < 8; ++i) {
            const int row = (i < 4) ? (4 * ty + i) : (64 + 4 * ty + (i - 4));
#pragma unroll
            for (int j = 0; j < 4; ++j)
                sm.Hs[row][4 * tx + j] = acc[i][4 * half + j];
        }
        __syncthreads();
#pragma unroll
        for (int p = 0; p < 4; ++p) {
            const int pair = (p << 8) + tid;
            const int ul = pair >> 7, bl = pair & 127;
            const int u = ub_base + half * 8 + ul;
            float h[HID];
#pragma unroll
            for (int j = 0; j < HID; ++j)
                h[j] = fmaxf(sm.Hs[bl][ul * 8 + j] + b0[u * 8 + j], 0.f);
            float h2[HID];
#pragma unroll
            for (int g = 0; g < HID; ++g) {
                float s = b1[u * 8 + g];
#pragma unroll
                for (int j = 0; j < HID; ++j) s += h[j] * W1[u * 64 + g * 8 + j];
                h2[g] = fmaxf(s, 0.f);
            }
            float best = b2[u * 16];
#pragma unroll
            for (int j = 0; j < HID; ++j) best += h2[j] * W2[u * 128 + j];
            int bi = 0;
#pragma unroll
            for (int a = 1; a < NACT; ++a) {
                float s = b2[u * 16 + a];
#pragma unroll
                for (int j = 0; j < HID; ++j) s += h2[j] * W2[u * 128 + a * 8 + j];
                if (s > best) { best = s; bi = a; }
            }
            outT[(size_t)u * B_TOTAL + m0 + bl] = (float)bi;
        }
    }
}

// Policy head (reads a1T fp32 [U][B], coalesced across lanes)
__global__ __launch_bounds__(256)
void policy_kernel(const float* __restrict__ A1T,
                   const float* __restrict__ PW0, const float* __restrict__ Pb0,
                   const float* __restrict__ PW1, const float* __restrict__ Pb1,
                   const float* __restrict__ PW2, const float* __restrict__ Pb2,
                   float* __restrict__ out)
{
    const int b = blockIdx.x * blockDim.x + threadIdx.x;
    if (b >= B_TOTAL) return;
    float hp[HID];
#pragma unroll
    for (int j = 0; j < HID; ++j) hp[j] = Pb0[j];
    for (int u = 0; u < U_UNITS; ++u) {
        const float v = A1T[(size_t)u * B_TOTAL + b];
#pragma unroll
        for (int j = 0; j < HID; ++j) hp[j] += v * PW0[j * U_UNITS + u];
    }
    float h[HID];
#pragma unroll
    for (int j = 0; j < HID; ++j) h[j] = fmaxf(hp[j], 0.f);
    float h2[HID];
#pragma unroll
    for (int g = 0; g < HID; ++g) {
        float s = Pb1[g];
#pragma unroll
        for (int j = 0; j < HID; ++j) s += h[j] * PW1[g * 8 + j];
        h2[g] = fmaxf(s, 0.f);
    }
    float o = Pb2[0];
#pragma unroll
    for (int j = 0; j < HID; ++j) o += h2[j] * PW2[j];
    out[b] = o;
}

// ============================================================================

extern "C" void kernel_launch(void* const* d_in, const int* in_sizes, int n_in,
                              void* d_out, int out_size, void* d_ws, size_t ws_size,
                              hipStream_t stream)
{
    const float* state = (const float*)d_in[0];
    const float* W0_0  = (const float*)d_in[1];
    const float* b0_0  = (const float*)d_in[2];
    const float* W1_0  = (const float*)d_in[3];
    const float* b1_0  = (const float*)d_in[4];
    const float* W2_0  = (const float*)d_in[5];
    const float* b2_0  = (const float*)d_in[6];
    const float* W0_1  = (const float*)d_in[7];
    const float* b0_1  = (const float*)d_in[8];
    const float* W1_1  = (const float*)d_in[9];
    const float* b1_1  = (const float*)d_in[10];
    const float* W2_1  = (const float*)d_in[11];
    const float* b2_1  = (const float*)d_in[12];
    const float* PW0   = (const float*)d_in[13];
    const float* Pb0   = (const float*)d_in[14];
    const float* PW1   = (const float*)d_in[15];
    const float* Pb1   = (const float*)d_in[16];
    const float* PW2   = (const float*)d_in[17];
    const float* Pb2   = (const float*)d_in[18];

    // ws layout (elements)
    const size_t SZ_STATE = (size_t)B_TOTAL * F_IN;
    const size_t SZ_W00   = (size_t)U_UNITS * HID * F_IN;
    const size_t SZ_W01   = (size_t)U_UNITS * HID * U_UNITS;
    const size_t NEED = (2 * SZ_STATE + 2 * SZ_W00 + 2 * SZ_W01
                         + (size_t)B_TOTAL * U_UNITS) * 2            // fp16 parts + a0
                        + (size_t)U_UNITS * B_TOTAL * 4;             // a1T fp32

    if (ws_size >= NEED) {
        char* p = (char*)d_ws;
        _Float16* state_h = (_Float16*)p;                p += SZ_STATE * 2;
        _Float16* state_l = (_Float16*)p;                p += SZ_STATE * 2;
        _Float16* w00_h   = (_Float16*)p;                p += SZ_W00 * 2;
        _Float16* w00_l   = (_Float16*)p;                p += SZ_W00 * 2;
        _Float16* w01_h   = (_Float16*)p;                p += SZ_W01 * 2;
        _Float16* w01_l   = (_Float16*)p;                p += SZ_W01 * 2;
        _Float16* a0      = (_Float16*)p;                p += (size_t)B_TOTAL * U_UNITS * 2;
        float*    a1T     = (float*)p;

        // pack fp32 -> fragment-ordered fp16 (h, l*2048)
        pack_kernel<true><<<(B_TOTAL / 16) * (F_IN / 128), 256, 0, stream>>>(
            state, state_h, state_l, F_IN);
        pack_kernel<true><<<(U_UNITS * HID / 16) * (F_IN / 128), 256, 0, stream>>>(
            W0_0, w00_h, w00_l, F_IN);
        pack_kernel<true><<<(U_UNITS * HID / 16) * (U_UNITS / 128), 256, 0, stream>>>(
            W0_1, w01_h, w01_l, U_UNITS);

        dim3 grid((U_UNITS * HID) / BN, B_TOTAL / BM);   // (16, 64)

        coagent_mfma<F_IN, true, false><<<grid, 256, 0, stream>>>(
            state_h, state_l, w00_h, w00_l, b0_0, W1_0, b1_0, W2_0, b2_0, (void*)a0);

        coagent_mfma<U_UNITS, false, true><<<grid, 256, 0, stream>>>(
            a0, nullptr, w01_h, w01_l, b0_1, W1_1, b1_1, W2_1, b2_1, (void*)a1T);

        policy_kernel<<<B_TOTAL / 256, 256, 0, stream>>>(
            a1T, PW0, Pb0, PW1, Pb1, PW2, Pb2, (float*)d_out);
    } else {
        // fp32 fallback (round-1 path, needs 16 MB ws)
        float* a0T = (float*)d_ws;
        float* a1T = a0T + (size_t)U_UNITS * B_TOTAL;
        dim3 grid((U_UNITS * HID) / FBN, B_TOTAL / FBM);
        coagent_kernel<F_IN, false><<<grid, 256, 0, stream>>>(
            state, W0_0, b0_0, W1_0, b1_0, W2_0, b2_0, a0T);
        coagent_kernel<U_UNITS, true><<<grid, 256, 0, stream>>>(
            a0T, W0_1, b0_1, W1_1, b1_1, W2_1, b2_1, a1T);
        policy_kernel<<<B_TOTAL / 256, 256, 0, stream>>>(
            a1T, PW0, Pb0, PW1, Pb1, PW2, Pb2, (float*)d_out);
    }
}